// Round 8
// baseline (415.727 us; speedup 1.0000x reference)
//
#include <hip/hip_runtime.h>
#include <stdint.h>

#define B_ 2
#define S_ 2048
#define D_ 1024
#define H_ 16
#define DH_ 64
#define M_ 4096
#define BS_ 4096

typedef __attribute__((ext_vector_type(8))) short short8;
typedef __attribute__((ext_vector_type(4))) float f32x4;
typedef __attribute__((ext_vector_type(16))) float f32x16;

static __device__ __forceinline__ unsigned short f2bf(float f) {
  unsigned u = __float_as_uint(f);
  u += 0x7fffu + ((u >> 16) & 1u);
  return (unsigned short)(u >> 16);
}
static __device__ __forceinline__ float bf2f(unsigned short s) {
  return __uint_as_float(((unsigned)s) << 16);
}
static __device__ __forceinline__ f32x4 MFMA16(short8 a, short8 b, f32x4 c) {
  return __builtin_amdgcn_mfma_f32_16x16x32_bf16(a, b, c, 0, 0, 0);
}
static __device__ __forceinline__ f32x16 MFMA32(short8 a, short8 b, f32x16 c) {
  return __builtin_amdgcn_mfma_f32_32x32x16_bf16(a, b, c, 0, 0, 0);
}
static __device__ __forceinline__ void gload_lds16(const void* g, void* l) {
  __builtin_amdgcn_global_load_lds(
      (const __attribute__((address_space(1))) unsigned int*)g,
      (__attribute__((address_space(3))) unsigned int*)l, 16, 0, 0);
}
static __device__ __forceinline__ unsigned cvtpk_bf16(float lo, float hi) {
  unsigned r;
  asm("v_cvt_pk_bf16_f32 %0, %1, %2" : "=v"(r) : "v"(lo), "v"(hi));
  return r;
}
static __device__ __forceinline__ float gelu_f(float x) {
  float u = 0.7978845608028654f * (x + 0.044715f * x * x * x);
  return 0.5f * x * (1.0f + tanhf(u));
}

// ---------------- transpose + cast fp32 -> bf16 ----------------
__global__ __launch_bounds__(256) void tcast_kernel(const float* __restrict__ in,
                                                    unsigned short* __restrict__ out,
                                                    int R, int C) {
  __shared__ float tile[32][33];
  int tx = threadIdx.x & 31, ty = threadIdx.x >> 5;
  int r0 = blockIdx.y * 32, c0 = blockIdx.x * 32;
#pragma unroll
  for (int i = 0; i < 4; ++i)
    tile[ty + i * 8][tx] = in[(size_t)(r0 + ty + i * 8) * C + c0 + tx];
  __syncthreads();
#pragma unroll
  for (int i = 0; i < 4; ++i)
    out[(size_t)(c0 + ty + i * 8) * R + r0 + tx] = f2bf(tile[tx][ty + i * 8]);
}

// ---------------- LayerNorm (f32 in, bf16 out) ----------------
__global__ __launch_bounds__(256) void ln_kernel(const float* __restrict__ x,
                                                 const float* __restrict__ sc,
                                                 const float* __restrict__ bi,
                                                 unsigned short* __restrict__ out) {
  int row = blockIdx.x;
  int t = threadIdx.x;
  float4 v = ((const float4*)(x + (size_t)row * D_))[t];
  float s1 = v.x + v.y + v.z + v.w;
  float s2 = v.x * v.x + v.y * v.y + v.z * v.z + v.w * v.w;
#pragma unroll
  for (int m = 1; m < 64; m <<= 1) {
    s1 += __shfl_xor(s1, m);
    s2 += __shfl_xor(s2, m);
  }
  __shared__ float red[8];
  int w = t >> 6, l = t & 63;
  if (l == 0) { red[w] = s1; red[4 + w] = s2; }
  __syncthreads();
  s1 = red[0] + red[1] + red[2] + red[3];
  s2 = red[4] + red[5] + red[6] + red[7];
  float mean = s1 * (1.0f / D_);
  float var = s2 * (1.0f / D_) - mean * mean;
  float rstd = rsqrtf(var + 1e-6f);
  float4 scv = ((const float4*)sc)[t];
  float4 biv = ((const float4*)bi)[t];
  ushort4 o;
  o.x = f2bf((v.x - mean) * rstd * scv.x + biv.x);
  o.y = f2bf((v.y - mean) * rstd * scv.y + biv.y);
  o.z = f2bf((v.z - mean) * rstd * scv.z + biv.z);
  o.w = f2bf((v.w - mean) * rstd * scv.w + biv.w);
  ((ushort4*)out)[(size_t)row * (D_ / 4) + t] = o;
}

// ---------------- RoPE (in-place on [B*H, S, DH] bf16), optional scale ----------------
__global__ __launch_bounds__(256) void rope_kernel(unsigned short* __restrict__ t_,
                                                   float qscale) {
  size_t idx = (size_t)blockIdx.x * 256 + threadIdx.x;  // B*H*S*8 threads
  int c = (int)(idx & 7);
  size_t rowi = idx >> 3;
  int s = (int)(rowi & (S_ - 1));
  unsigned short* p = t_ + rowi * DH_ + c * 8;
  short8 v = *(const short8*)p;
  unsigned short o[8];
#pragma unroll
  for (int i = 0; i < 4; ++i) {
    int pi = c * 4 + i;  // pair index 0..31
    float freq = exp2f(-(float)pi * 0.4152410118609203f);  // 10000^(-pi/32)
    float ang = (float)s * freq;
    float sn, cs;
    sincosf(ang, &sn, &cs);
    float a = bf2f((unsigned short)v[2 * i]);
    float b = bf2f((unsigned short)v[2 * i + 1]);
    o[2 * i] = f2bf((a * cs - b * sn) * qscale);
    o[2 * i + 1] = f2bf((a * sn + b * cs) * qscale);
  }
  short8 ov;
#pragma unroll
  for (int i = 0; i < 8; ++i) ov[i] = (short)o[i];
  *(short8*)p = ov;
}

// ---------------- Flash attention, 32x32 MFMA, no-max softmax (log2 domain) ----
// (round-5 version: known 72.6us, absmax 0.03125)
__global__ __launch_bounds__(256) void attn_kernel(const unsigned short* __restrict__ q,
                                                   const unsigned short* __restrict__ k,
                                                   const unsigned short* __restrict__ vt,
                                                   unsigned short* __restrict__ ctx) {
  __shared__ char smem[49152];  // 2x(Ks 8K | Vs 8K) | Ps 4x4K
  const int tid = threadIdx.x, w = tid >> 6, l = tid & 63;
  const int lo = l & 31, hi = l >> 5;
  char* Ps = smem + 32768 + w * 4096;
  int flat = blockIdx.y * 16 + blockIdx.x;
  int swz = (flat & 7) * 64 + (flat >> 3);
  const int bh = swz >> 4;
  const int b = bh >> 4, h = bh & 15;
  const int q0 = (swz & 15) * 128 + w * 32;

  const unsigned short* qbase = q + ((size_t)bh * S_ + q0 + lo) * DH_ + hi * 8;
  short8 qf[4];
#pragma unroll
  for (int c = 0; c < 4; ++c) qf[c] = *(const short8*)(qbase + c * 16);

  const unsigned short* kb = k + (size_t)bh * S_ * DH_;
  const unsigned short* vb = vt + (size_t)bh * DH_ * S_;

  short8 onesB;
#pragma unroll
  for (int i = 0; i < 8; ++i) onesB[i] = (short)0x3F80;  // bf16 1.0

  f32x16 o0, o1, lac;
#pragma unroll
  for (int i = 0; i < 16; ++i) { o0[i] = 0.f; o1[i] = 0.f; lac[i] = 0.f; }

#define STAGE_KV(buf, kt)                                                        \
  {                                                                              \
    char* Ks_ = smem + (buf) * 16384;                                            \
    char* Vs_ = Ks_ + 8192;                                                      \
    _Pragma("unroll") for (int i = 0; i < 2; ++i) {                              \
      int slot = i * 256 + tid;                                                  \
      int r = slot >> 3, pc = slot & 7;                                          \
      int sc_ = pc ^ (r & 7);                                                    \
      gload_lds16(kb + (size_t)((kt) + r) * DH_ + sc_ * 8,                       \
                  Ks_ + (i * 4096 + w * 1024));                                  \
      gload_lds16(vb + (size_t)r * S_ + (kt) + sc_ * 8,                          \
                  Vs_ + (i * 4096 + w * 1024));                                  \
    }                                                                            \
  }

  STAGE_KV(0, 0);
  asm volatile("s_waitcnt vmcnt(0)" ::: "memory");
  __builtin_amdgcn_s_barrier();

  for (int t = 0; t < S_ / 64; ++t) {
    int buf = t & 1;
    if (t + 1 < S_ / 64) STAGE_KV(buf ^ 1, (t + 1) * 64);
    char* Ks = smem + buf * 16384;
    char* Vs = Ks + 8192;

#pragma unroll
    for (int kt2 = 0; kt2 < 2; ++kt2) {
      f32x16 z;
#pragma unroll
      for (int i = 0; i < 16; ++i) z[i] = 0.f;
      __builtin_amdgcn_s_setprio(1);
#pragma unroll
      for (int c = 0; c < 4; ++c) {
        int r = kt2 * 32 + lo;
        short8 kf = *(const short8*)(Ks + r * 128 + (((hi + 2 * c) ^ (r & 7)) << 4));
        z = MFMA32(kf, qf[c], z);
      }
      __builtin_amdgcn_s_setprio(0);
      unsigned pk[8];
#pragma unroll
      for (int e = 0; e < 8; ++e)
        pk[e] = cvtpk_bf16(exp2f(z[2 * e]), exp2f(z[2 * e + 1]));
#pragma unroll
      for (int s2 = 0; s2 < 4; ++s2) {
        uint2 dd;
        dd.x = pk[2 * s2];
        dd.y = pk[2 * s2 + 1];
        int slot = kt2 * 4 + s2;
        *(uint2*)(Ps + lo * 128 + ((slot ^ (lo & 7)) << 4) + hi * 8) = dd;
      }
    }

    __builtin_amdgcn_s_setprio(1);
#pragma unroll
    for (int c = 0; c < 4; ++c) {
      short8 pa = *(const short8*)(Ps + lo * 128 + (((2 * c + hi) ^ (lo & 7)) << 4));
      lac = MFMA32(pa, onesB, lac);
      int r0v = lo, r1v = 32 + lo;
      short8 vf0 = *(const short8*)(Vs + r0v * 128 + (((2 * c + hi) ^ (r0v & 7)) << 4));
      short8 vf1 = *(const short8*)(Vs + r1v * 128 + (((2 * c + hi) ^ (r1v & 7)) << 4));
      o0 = MFMA32(pa, vf0, o0);
      o1 = MFMA32(pa, vf1, o1);
    }
    __builtin_amdgcn_s_setprio(0);
    asm volatile("s_waitcnt vmcnt(0)" ::: "memory");
    __builtin_amdgcn_s_barrier();
  }

#pragma unroll
  for (int r = 0; r < 16; ++r) {
    float rl = 1.0f / lac[r];
    int srow = q0 + (r & 3) + 8 * (r >> 2) + 4 * hi;
    unsigned short* cp = ctx + ((size_t)(b * S_) + srow) * D_ + h * DH_ + lo;
    cp[0] = f2bf(o0[r] * rl);
    cp[32] = f2bf(o1[r] * rl);
  }
#undef STAGE_KV
}

// ---------------- GEMM, 3-deep counted-vmcnt pipeline (T4) ----------------
// C[M,N] = A[M,K] * Bt[N,K]^T, bf16 in, f32 acc. 128x128 tile, BK=64.
// LDS = 3 x 32KB buffers (dynamic 96KB). Steady state: vmcnt(8) waits only for
// tile t's 8 staging loads; tile t+1's 8 stay in flight across the barrier.
// EPI 0: QKV scatter  EPI 1: +x -> f32  EPI 2: +b1,gelu -> bf16  EPI 3: +b2+mlp_in -> f32
template <int EPI>
__global__ __launch_bounds__(256) void gemm3p(const unsigned short* __restrict__ A,
                                              const unsigned short* __restrict__ Bt,
                                              int K,
                                              const float* __restrict__ aux0,
                                              const float* __restrict__ aux1,
                                              void* __restrict__ out0,
                                              void* __restrict__ out1,
                                              void* __restrict__ out2) {
  extern __shared__ char smem[];  // 3 x (As 16K | Bs 16K)
  int tid = threadIdx.x, w = tid >> 6, l = tid & 63;
  int wr = w >> 1, wc = w & 1;
  // XCD-aware bijective swizzle (all grids have nwg % 8 == 0)
  int gx = gridDim.x;
  int nwg = gx * gridDim.y;
  int flat = blockIdx.y * gx + blockIdx.x;
  int swz = (flat & 7) * (nwg >> 3) + (flat >> 3);
  int row0 = (swz / gx) * 128, col0 = (swz % gx) * 128;
  f32x4 acc[4][4];
#pragma unroll
  for (int mt = 0; mt < 4; ++mt)
#pragma unroll
    for (int nt = 0; nt < 4; ++nt) {
      f32x4 z = {0.f, 0.f, 0.f, 0.f};
      acc[mt][nt] = z;
    }
  int lr = l >> 3, lc = l & 7;

#define STAGE_AB(base, kt)                                                       \
  {                                                                              \
    char* As_ = smem + (base);                                                   \
    char* Bs_ = As_ + 16384;                                                     \
    _Pragma("unroll") for (int i = 0; i < 4; ++i) {                              \
      int rb = w * 32 + i * 8;                                                   \
      int r = rb + lr;                                                           \
      int sc_ = lc ^ (r & 7);                                                    \
      gload_lds16(A + (size_t)(row0 + r) * K + (kt) + sc_ * 8, As_ + rb * 128);  \
      gload_lds16(Bt + (size_t)(col0 + r) * K + (kt) + sc_ * 8, Bs_ + rb * 128); \
    }                                                                            \
  }

#define COMPUTE_STEP(As, Bs)                                                     \
  {                                                                              \
    _Pragma("unroll") for (int kf = 0; kf < 2; ++kf) {                           \
      short8 af[4], bfr[4];                                                      \
      _Pragma("unroll") for (int mt = 0; mt < 4; ++mt) {                         \
        int r = wr * 64 + mt * 16 + (l & 15);                                    \
        int c = (l >> 4) + 4 * kf;                                               \
        af[mt] = *(const short8*)((As) + r * 128 + ((c ^ (r & 7)) << 4));        \
      }                                                                          \
      _Pragma("unroll") for (int nt = 0; nt < 4; ++nt) {                         \
        int r = wc * 64 + nt * 16 + (l & 15);                                    \
        int c = (l >> 4) + 4 * kf;                                               \
        bfr[nt] = *(const short8*)((Bs) + r * 128 + ((c ^ (r & 7)) << 4));       \
      }                                                                          \
      _Pragma("unroll") for (int mt = 0; mt < 4; ++mt)                           \
          _Pragma("unroll") for (int nt = 0; nt < 4; ++nt)                       \
              acc[mt][nt] = MFMA16(af[mt], bfr[nt], acc[mt][nt]);                \
    }                                                                            \
  }

  const int NT = K >> 6;  // >= 16 for all our GEMMs
  STAGE_AB(0, 0);
  STAGE_AB(32768, 64);
  int cb = 0;  // compute buffer base/32768 for iter t
  int sb = 2;  // stage buffer for iter t+2
  for (int t = 0; t < NT; ++t) {
    // wait for tile t's loads only; tile t+1's (8) stay in flight
    if (t + 1 < NT)
      asm volatile("s_waitcnt vmcnt(8)" ::: "memory");
    else
      asm volatile("s_waitcnt vmcnt(0)" ::: "memory");
    __builtin_amdgcn_s_barrier();  // buf cb ready; compute(t-1) done -> buf sb reusable
    if (t + 2 < NT) STAGE_AB(sb * 32768, (t + 2) * 64);
    char* As = smem + cb * 32768;
    COMPUTE_STEP(As, As + 16384);
    cb = (cb == 2) ? 0 : cb + 1;
    sb = (sb == 2) ? 0 : sb + 1;
  }
#undef STAGE_AB
#undef COMPUTE_STEP

  // epilogue
#pragma unroll
  for (int mt = 0; mt < 4; ++mt) {
#pragma unroll
    for (int nt = 0; nt < 4; ++nt) {
      int grow0 = row0 + wr * 64 + mt * 16 + ((l >> 4) << 2);
      int gcol = col0 + wc * 64 + nt * 16 + (l & 15);
      if (EPI == 0) {
        int which = gcol >> 10;
        int d = gcol & 1023;
        int hh = d >> 6, dh = d & 63;
#pragma unroll
        for (int r = 0; r < 4; ++r) {
          int grow = grow0 + r;
          int b = grow >> 11, s = grow & 2047;
          float v = acc[mt][nt][r];
          if (which == 0)
            ((unsigned short*)out0)[(((size_t)(b * H_ + hh)) * S_ + s) * DH_ + dh] = f2bf(v);
          else if (which == 1)
            ((unsigned short*)out1)[(((size_t)(b * H_ + hh)) * S_ + s) * DH_ + dh] = f2bf(v);
          else
            ((unsigned short*)out2)[(((size_t)(b * H_ + hh)) * DH_ + dh) * S_ + s] = f2bf(v);
        }
      } else if (EPI == 1) {
        float* mo = (float*)out0;
#pragma unroll
        for (int r = 0; r < 4; ++r) {
          int grow = grow0 + r;
          mo[(size_t)grow * D_ + gcol] = acc[mt][nt][r] + aux0[(size_t)grow * D_ + gcol];
        }
      } else if (EPI == 2) {
        unsigned short* gq = (unsigned short*)out0;
        float bb = aux0[gcol];
#pragma unroll
        for (int r = 0; r < 4; ++r) {
          int grow = grow0 + r;
          gq[(size_t)grow * M_ + gcol] = f2bf(gelu_f(acc[mt][nt][r] + bb));
        }
      } else {
        float* po = (float*)out0;
        float bb = aux0[gcol];
#pragma unroll
        for (int r = 0; r < 4; ++r) {
          int grow = grow0 + r;
          po[(size_t)grow * D_ + gcol] =
              acc[mt][nt][r] + bb + aux1[(size_t)grow * D_ + gcol];
        }
      }
    }
  }
}

extern "C" void kernel_launch(void* const* d_in, const int* in_sizes, int n_in,
                              void* d_out, int out_size, void* d_ws, size_t ws_size,
                              hipStream_t stream) {
  const float* x = (const float*)d_in[0];
  const float* ln1s = (const float*)d_in[1];
  const float* ln1b = (const float*)d_in[2];
  const float* wk = (const float*)d_in[3];
  const float* wq = (const float*)d_in[4];
  const float* wv = (const float*)d_in[5];
  const float* wo = (const float*)d_in[6];
  const float* ln2s = (const float*)d_in[7];
  const float* ln2b = (const float*)d_in[8];
  const float* w1 = (const float*)d_in[9];
  const float* b1 = (const float*)d_in[10];
  const float* w2 = (const float*)d_in[11];
  const float* b2 = (const float*)d_in[12];

  char* ws = (char*)d_ws;
  unsigned short* wqkv_t = (unsigned short*)(ws);              // [3072,1024]
  unsigned short* wo_t = (unsigned short*)(ws + 6291456);      // [1024,1024]
  unsigned short* w1_t = (unsigned short*)(ws + 8388608);      // [4096,1024]
  unsigned short* w2_t = (unsigned short*)(ws + 16777216);     // [1024,4096]
  unsigned short* h_bf = (unsigned short*)(ws + 25165824);     // [4096,1024] (reused for h2)
  unsigned short* q_bf = (unsigned short*)(ws + 33554432);     // [B,H,S,DH]
  unsigned short* k_bf = (unsigned short*)(ws + 41943040);     // [B,H,S,DH]
  unsigned short* vt_bf = (unsigned short*)(ws + 50331648);    // [B,H,DH,S]
  unsigned short* ctx_bf = (unsigned short*)(ws + 58720256);   // [B,S,D]
  float* mlp_in = (float*)(ws + 67108864);                     // [4096,1024] f32
  unsigned short* g_bf = (unsigned short*)(ws + 83886080);     // [4096,4096]

  // allow 96KB dynamic LDS for the pipelined GEMMs (host-side, graph-safe)
  hipFuncSetAttribute((const void*)gemm3p<0>,
                      hipFuncAttributeMaxDynamicSharedMemorySize, 98304);
  hipFuncSetAttribute((const void*)gemm3p<1>,
                      hipFuncAttributeMaxDynamicSharedMemorySize, 98304);
  hipFuncSetAttribute((const void*)gemm3p<2>,
                      hipFuncAttributeMaxDynamicSharedMemorySize, 98304);
  hipFuncSetAttribute((const void*)gemm3p<3>,
                      hipFuncAttributeMaxDynamicSharedMemorySize, 98304);

  dim3 blk(256);
  tcast_kernel<<<dim3(32, 32), blk, 0, stream>>>(wq, wqkv_t, 1024, 1024);
  tcast_kernel<<<dim3(32, 32), blk, 0, stream>>>(wk, wqkv_t + 1048576, 1024, 1024);
  tcast_kernel<<<dim3(32, 32), blk, 0, stream>>>(wv, wqkv_t + 2097152, 1024, 1024);
  tcast_kernel<<<dim3(32, 32), blk, 0, stream>>>(wo, wo_t, 1024, 1024);
  tcast_kernel<<<dim3(128, 32), blk, 0, stream>>>(w1, w1_t, 1024, 4096);
  tcast_kernel<<<dim3(32, 128), blk, 0, stream>>>(w2, w2_t, 4096, 1024);
  ln_kernel<<<dim3(BS_), blk, 0, stream>>>(x, ln1s, ln1b, h_bf);
  gemm3p<0><<<dim3(24, 32), blk, 98304, stream>>>(h_bf, wqkv_t, 1024, nullptr, nullptr,
                                                  q_bf, k_bf, vt_bf);
  // q scaled by 1/sqrt(DH) * log2(e) so attention scores are in exp2 domain
  rope_kernel<<<dim3(2048), blk, 0, stream>>>(q_bf, 0.125f * 1.4426950408889634f);
  rope_kernel<<<dim3(2048), blk, 0, stream>>>(k_bf, 1.0f);
  attn_kernel<<<dim3(16, 32), blk, 0, stream>>>(q_bf, k_bf, vt_bf, ctx_bf);
  gemm3p<1><<<dim3(8, 32), blk, 98304, stream>>>(ctx_bf, wo_t, 1024, x, nullptr,
                                                 mlp_in, nullptr, nullptr);
  ln_kernel<<<dim3(BS_), blk, 0, stream>>>(mlp_in, ln2s, ln2b, h_bf);
  gemm3p<2><<<dim3(32, 32), blk, 98304, stream>>>(h_bf, w1_t, 1024, b1, nullptr,
                                                  g_bf, nullptr, nullptr);
  gemm3p<3><<<dim3(8, 32), blk, 98304, stream>>>(g_bf, w2_t, 4096, b2, mlp_in,
                                                 (float*)d_out, nullptr, nullptr);
}

// Round 9
// 373.796 us; speedup vs baseline: 1.1122x; 1.1122x over previous
//
#include <hip/hip_runtime.h>
#include <stdint.h>

#define B_ 2
#define S_ 2048
#define D_ 1024
#define H_ 16
#define DH_ 64
#define M_ 4096
#define BS_ 4096

typedef __attribute__((ext_vector_type(8))) short short8;
typedef __attribute__((ext_vector_type(4))) float f32x4;
typedef __attribute__((ext_vector_type(16))) float f32x16;

static __device__ __forceinline__ unsigned short f2bf(float f) {
  unsigned u = __float_as_uint(f);
  u += 0x7fffu + ((u >> 16) & 1u);
  return (unsigned short)(u >> 16);
}
static __device__ __forceinline__ float bf2f(unsigned short s) {
  return __uint_as_float(((unsigned)s) << 16);
}
static __device__ __forceinline__ f32x4 MFMA16(short8 a, short8 b, f32x4 c) {
  return __builtin_amdgcn_mfma_f32_16x16x32_bf16(a, b, c, 0, 0, 0);
}
static __device__ __forceinline__ f32x16 MFMA32(short8 a, short8 b, f32x16 c) {
  return __builtin_amdgcn_mfma_f32_32x32x16_bf16(a, b, c, 0, 0, 0);
}
static __device__ __forceinline__ void gload_lds16(const void* g, void* l) {
  __builtin_amdgcn_global_load_lds(
      (const __attribute__((address_space(1))) unsigned int*)g,
      (__attribute__((address_space(3))) unsigned int*)l, 16, 0, 0);
}
static __device__ __forceinline__ unsigned cvtpk_bf16(float lo, float hi) {
  unsigned r;
  asm("v_cvt_pk_bf16_f32 %0, %1, %2" : "=v"(r) : "v"(lo), "v"(hi));
  return r;
}
static __device__ __forceinline__ float gelu_f(float x) {
  float u = 0.7978845608028654f * (x + 0.044715f * x * x * x);
  return 0.5f * x * (1.0f + tanhf(u));
}

// ---------------- transpose + cast fp32 -> bf16 ----------------
__global__ __launch_bounds__(256) void tcast_kernel(const float* __restrict__ in,
                                                    unsigned short* __restrict__ out,
                                                    int R, int C) {
  __shared__ float tile[32][33];
  int tx = threadIdx.x & 31, ty = threadIdx.x >> 5;
  int r0 = blockIdx.y * 32, c0 = blockIdx.x * 32;
#pragma unroll
  for (int i = 0; i < 4; ++i)
    tile[ty + i * 8][tx] = in[(size_t)(r0 + ty + i * 8) * C + c0 + tx];
  __syncthreads();
#pragma unroll
  for (int i = 0; i < 4; ++i)
    out[(size_t)(c0 + ty + i * 8) * R + r0 + tx] = f2bf(tile[tx][ty + i * 8]);
}

// ---------------- LayerNorm (f32 in, bf16 out) ----------------
__global__ __launch_bounds__(256) void ln_kernel(const float* __restrict__ x,
                                                 const float* __restrict__ sc,
                                                 const float* __restrict__ bi,
                                                 unsigned short* __restrict__ out) {
  int row = blockIdx.x;
  int t = threadIdx.x;
  float4 v = ((const float4*)(x + (size_t)row * D_))[t];
  float s1 = v.x + v.y + v.z + v.w;
  float s2 = v.x * v.x + v.y * v.y + v.z * v.z + v.w * v.w;
#pragma unroll
  for (int m = 1; m < 64; m <<= 1) {
    s1 += __shfl_xor(s1, m);
    s2 += __shfl_xor(s2, m);
  }
  __shared__ float red[8];
  int w = t >> 6, l = t & 63;
  if (l == 0) { red[w] = s1; red[4 + w] = s2; }
  __syncthreads();
  s1 = red[0] + red[1] + red[2] + red[3];
  s2 = red[4] + red[5] + red[6] + red[7];
  float mean = s1 * (1.0f / D_);
  float var = s2 * (1.0f / D_) - mean * mean;
  float rstd = rsqrtf(var + 1e-6f);
  float4 scv = ((const float4*)sc)[t];
  float4 biv = ((const float4*)bi)[t];
  ushort4 o;
  o.x = f2bf((v.x - mean) * rstd * scv.x + biv.x);
  o.y = f2bf((v.y - mean) * rstd * scv.y + biv.y);
  o.z = f2bf((v.z - mean) * rstd * scv.z + biv.z);
  o.w = f2bf((v.w - mean) * rstd * scv.w + biv.w);
  ((ushort4*)out)[(size_t)row * (D_ / 4) + t] = o;
}

// ---------------- RoPE (in-place on [B*H, S, DH] bf16), optional scale ----------------
__global__ __launch_bounds__(256) void rope_kernel(unsigned short* __restrict__ t_,
                                                   float qscale) {
  size_t idx = (size_t)blockIdx.x * 256 + threadIdx.x;  // B*H*S*8 threads
  int c = (int)(idx & 7);
  size_t rowi = idx >> 3;
  int s = (int)(rowi & (S_ - 1));
  unsigned short* p = t_ + rowi * DH_ + c * 8;
  short8 v = *(const short8*)p;
  unsigned short o[8];
#pragma unroll
  for (int i = 0; i < 4; ++i) {
    int pi = c * 4 + i;  // pair index 0..31
    float freq = exp2f(-(float)pi * 0.4152410118609203f);  // 10000^(-pi/32)
    float ang = (float)s * freq;
    float sn, cs;
    sincosf(ang, &sn, &cs);
    float a = bf2f((unsigned short)v[2 * i]);
    float b = bf2f((unsigned short)v[2 * i + 1]);
    o[2 * i] = f2bf((a * cs - b * sn) * qscale);
    o[2 * i + 1] = f2bf((a * sn + b * cs) * qscale);
  }
  short8 ov;
#pragma unroll
  for (int i = 0; i < 8; ++i) ov[i] = (short)o[i];
  *(short8*)p = ov;
}

// ---------------- Flash attention, 32x32 MFMA, no-max softmax (log2 domain) ----
// (round-5 version: known 72.6us, absmax 0.03125)
__global__ __launch_bounds__(256) void attn_kernel(const unsigned short* __restrict__ q,
                                                   const unsigned short* __restrict__ k,
                                                   const unsigned short* __restrict__ vt,
                                                   unsigned short* __restrict__ ctx) {
  __shared__ char smem[49152];  // 2x(Ks 8K | Vs 8K) | Ps 4x4K
  const int tid = threadIdx.x, w = tid >> 6, l = tid & 63;
  const int lo = l & 31, hi = l >> 5;
  char* Ps = smem + 32768 + w * 4096;
  int flat = blockIdx.y * 16 + blockIdx.x;
  int swz = (flat & 7) * 64 + (flat >> 3);
  const int bh = swz >> 4;
  const int b = bh >> 4, h = bh & 15;
  const int q0 = (swz & 15) * 128 + w * 32;

  const unsigned short* qbase = q + ((size_t)bh * S_ + q0 + lo) * DH_ + hi * 8;
  short8 qf[4];
#pragma unroll
  for (int c = 0; c < 4; ++c) qf[c] = *(const short8*)(qbase + c * 16);

  const unsigned short* kb = k + (size_t)bh * S_ * DH_;
  const unsigned short* vb = vt + (size_t)bh * DH_ * S_;

  short8 onesB;
#pragma unroll
  for (int i = 0; i < 8; ++i) onesB[i] = (short)0x3F80;  // bf16 1.0

  f32x16 o0, o1, lac;
#pragma unroll
  for (int i = 0; i < 16; ++i) { o0[i] = 0.f; o1[i] = 0.f; lac[i] = 0.f; }

#define STAGE_KV(buf, kt)                                                        \
  {                                                                              \
    char* Ks_ = smem + (buf) * 16384;                                            \
    char* Vs_ = Ks_ + 8192;                                                      \
    _Pragma("unroll") for (int i = 0; i < 2; ++i) {                              \
      int slot = i * 256 + tid;                                                  \
      int r = slot >> 3, pc = slot & 7;                                          \
      int sc_ = pc ^ (r & 7);                                                    \
      gload_lds16(kb + (size_t)((kt) + r) * DH_ + sc_ * 8,                       \
                  Ks_ + (i * 4096 + w * 1024));                                  \
      gload_lds16(vb + (size_t)r * S_ + (kt) + sc_ * 8,                          \
                  Vs_ + (i * 4096 + w * 1024));                                  \
    }                                                                            \
  }

  STAGE_KV(0, 0);
  asm volatile("s_waitcnt vmcnt(0)" ::: "memory");
  __builtin_amdgcn_s_barrier();

  for (int t = 0; t < S_ / 64; ++t) {
    int buf = t & 1;
    if (t + 1 < S_ / 64) STAGE_KV(buf ^ 1, (t + 1) * 64);
    char* Ks = smem + buf * 16384;
    char* Vs = Ks + 8192;

#pragma unroll
    for (int kt2 = 0; kt2 < 2; ++kt2) {
      f32x16 z;
#pragma unroll
      for (int i = 0; i < 16; ++i) z[i] = 0.f;
      __builtin_amdgcn_s_setprio(1);
#pragma unroll
      for (int c = 0; c < 4; ++c) {
        int r = kt2 * 32 + lo;
        short8 kf = *(const short8*)(Ks + r * 128 + (((hi + 2 * c) ^ (r & 7)) << 4));
        z = MFMA32(kf, qf[c], z);
      }
      __builtin_amdgcn_s_setprio(0);
      unsigned pk[8];
#pragma unroll
      for (int e = 0; e < 8; ++e)
        pk[e] = cvtpk_bf16(exp2f(z[2 * e]), exp2f(z[2 * e + 1]));
#pragma unroll
      for (int s2 = 0; s2 < 4; ++s2) {
        uint2 dd;
        dd.x = pk[2 * s2];
        dd.y = pk[2 * s2 + 1];
        int slot = kt2 * 4 + s2;
        *(uint2*)(Ps + lo * 128 + ((slot ^ (lo & 7)) << 4) + hi * 8) = dd;
      }
    }

    __builtin_amdgcn_s_setprio(1);
#pragma unroll
    for (int c = 0; c < 4; ++c) {
      short8 pa = *(const short8*)(Ps + lo * 128 + (((2 * c + hi) ^ (lo & 7)) << 4));
      lac = MFMA32(pa, onesB, lac);
      int r0v = lo, r1v = 32 + lo;
      short8 vf0 = *(const short8*)(Vs + r0v * 128 + (((2 * c + hi) ^ (r0v & 7)) << 4));
      short8 vf1 = *(const short8*)(Vs + r1v * 128 + (((2 * c + hi) ^ (r1v & 7)) << 4));
      o0 = MFMA32(pa, vf0, o0);
      o1 = MFMA32(pa, vf1, o1);
    }
    __builtin_amdgcn_s_setprio(0);
    asm volatile("s_waitcnt vmcnt(0)" ::: "memory");
    __builtin_amdgcn_s_barrier();
  }

#pragma unroll
  for (int r = 0; r < 16; ++r) {
    float rl = 1.0f / lac[r];
    int srow = q0 + (r & 3) + 8 * (r >> 2) + 4 * hi;
    unsigned short* cp = ctx + ((size_t)(b * S_) + srow) * D_ + h * DH_ + lo;
    cp[0] = f2bf(o0[r] * rl);
    cp[32] = f2bf(o1[r] * rl);
  }
#undef STAGE_KV
}

// ---------------- GEMM: C[M,N] = A[M,K] * Bt[N,K]^T, bf16 in, f32 acc ----------------
// Double-buffered 64KB (round-5 proven structure) + L2 group-major block mapping:
// xcd = dispatch%8 owns a 4-row band; within-XCD order is column-slow so the
// ~64 co-resident blocks per XCD form a 4-row x 16-col footprint (20 panels
// ~5MB ~ L2) instead of 2x32 (34 panels, 8.5MB thrash).
// EPI 0: QKV scatter   EPI 1: + x -> f32   EPI 2: + b1, gelu -> bf16
// EPI 3: + b2 + mlp_in -> f32
template <int EPI>
__global__ __launch_bounds__(256) void gemm_bt(const unsigned short* __restrict__ A,
                                               const unsigned short* __restrict__ Bt,
                                               int K,
                                               const float* __restrict__ aux0,
                                               const float* __restrict__ aux1,
                                               void* __restrict__ out0,
                                               void* __restrict__ out1,
                                               void* __restrict__ out2) {
  __shared__ char smem[65536];  // 2 x (As 16K | Bs 16K)
  int tid = threadIdx.x, w = tid >> 6, l = tid & 63;
  int wr = w >> 1, wc = w & 1;
  // group-major XCD mapping (all grids: gridDim.y == 32 rows, rows%8==0)
  int flat = blockIdx.y * gridDim.x + blockIdx.x;  // dispatch order
  int xcd = flat & 7, j = flat >> 3;
  int row0 = (xcd * 4 + (j & 3)) * 128;
  int col0 = (j >> 2) * 128;
  f32x4 acc[4][4];
#pragma unroll
  for (int mt = 0; mt < 4; ++mt)
#pragma unroll
    for (int nt = 0; nt < 4; ++nt) {
      f32x4 z = {0.f, 0.f, 0.f, 0.f};
      acc[mt][nt] = z;
    }
  int lr = l >> 3, lc = l & 7;

#define STAGE_AB(base, kt)                                                       \
  {                                                                              \
    char* As_ = smem + (base);                                                   \
    char* Bs_ = As_ + 16384;                                                     \
    _Pragma("unroll") for (int i = 0; i < 4; ++i) {                              \
      int rb = w * 32 + i * 8;                                                   \
      int r = rb + lr;                                                           \
      int sc_ = lc ^ (r & 7);                                                    \
      gload_lds16(A + (size_t)(row0 + r) * K + (kt) + sc_ * 8, As_ + rb * 128);  \
      gload_lds16(Bt + (size_t)(col0 + r) * K + (kt) + sc_ * 8, Bs_ + rb * 128); \
    }                                                                            \
  }

#define COMPUTE_STEP(As, Bs)                                                     \
  {                                                                              \
    _Pragma("unroll") for (int kf = 0; kf < 2; ++kf) {                           \
      short8 af[4], bfr[4];                                                      \
      _Pragma("unroll") for (int mt = 0; mt < 4; ++mt) {                         \
        int r = wr * 64 + mt * 16 + (l & 15);                                    \
        int c = (l >> 4) + 4 * kf;                                               \
        af[mt] = *(const short8*)((As) + r * 128 + ((c ^ (r & 7)) << 4));        \
      }                                                                          \
      _Pragma("unroll") for (int nt = 0; nt < 4; ++nt) {                         \
        int r = wc * 64 + nt * 16 + (l & 15);                                    \
        int c = (l >> 4) + 4 * kf;                                               \
        bfr[nt] = *(const short8*)((Bs) + r * 128 + ((c ^ (r & 7)) << 4));       \
      }                                                                          \
      _Pragma("unroll") for (int mt = 0; mt < 4; ++mt)                           \
          _Pragma("unroll") for (int nt = 0; nt < 4; ++nt)                       \
              acc[mt][nt] = MFMA16(af[mt], bfr[nt], acc[mt][nt]);                \
    }                                                                            \
  }

  const int NT = K >> 6;
  STAGE_AB(0, 0);
  asm volatile("s_waitcnt vmcnt(0)" ::: "memory");
  __builtin_amdgcn_s_barrier();
  for (int t = 0; t < NT; ++t) {
    int buf = t & 1;
    if (t + 1 < NT) STAGE_AB((buf ^ 1) * 32768, (t + 1) * 64);
    char* As = smem + buf * 32768;
    COMPUTE_STEP(As, As + 16384);
    asm volatile("s_waitcnt vmcnt(0)" ::: "memory");
    __builtin_amdgcn_s_barrier();
  }
#undef STAGE_AB
#undef COMPUTE_STEP

  // epilogue
#pragma unroll
  for (int mt = 0; mt < 4; ++mt) {
#pragma unroll
    for (int nt = 0; nt < 4; ++nt) {
      int grow0 = row0 + wr * 64 + mt * 16 + ((l >> 4) << 2);
      int gcol = col0 + wc * 64 + nt * 16 + (l & 15);
      if (EPI == 0) {
        int which = gcol >> 10;
        int d = gcol & 1023;
        int hh = d >> 6, dh = d & 63;
#pragma unroll
        for (int r = 0; r < 4; ++r) {
          int grow = grow0 + r;
          int b = grow >> 11, s = grow & 2047;
          float v = acc[mt][nt][r];
          if (which == 0)
            ((unsigned short*)out0)[(((size_t)(b * H_ + hh)) * S_ + s) * DH_ + dh] = f2bf(v);
          else if (which == 1)
            ((unsigned short*)out1)[(((size_t)(b * H_ + hh)) * S_ + s) * DH_ + dh] = f2bf(v);
          else
            ((unsigned short*)out2)[(((size_t)(b * H_ + hh)) * DH_ + dh) * S_ + s] = f2bf(v);
        }
      } else if (EPI == 1) {
        float* mo = (float*)out0;
#pragma unroll
        for (int r = 0; r < 4; ++r) {
          int grow = grow0 + r;
          mo[(size_t)grow * D_ + gcol] = acc[mt][nt][r] + aux0[(size_t)grow * D_ + gcol];
        }
      } else if (EPI == 2) {
        unsigned short* gq = (unsigned short*)out0;
        float bb = aux0[gcol];
#pragma unroll
        for (int r = 0; r < 4; ++r) {
          int grow = grow0 + r;
          gq[(size_t)grow * M_ + gcol] = f2bf(gelu_f(acc[mt][nt][r] + bb));
        }
      } else {
        float* po = (float*)out0;
        float bb = aux0[gcol];
#pragma unroll
        for (int r = 0; r < 4; ++r) {
          int grow = grow0 + r;
          po[(size_t)grow * D_ + gcol] =
              acc[mt][nt][r] + bb + aux1[(size_t)grow * D_ + gcol];
        }
      }
    }
  }
}

extern "C" void kernel_launch(void* const* d_in, const int* in_sizes, int n_in,
                              void* d_out, int out_size, void* d_ws, size_t ws_size,
                              hipStream_t stream) {
  const float* x = (const float*)d_in[0];
  const float* ln1s = (const float*)d_in[1];
  const float* ln1b = (const float*)d_in[2];
  const float* wk = (const float*)d_in[3];
  const float* wq = (const float*)d_in[4];
  const float* wv = (const float*)d_in[5];
  const float* wo = (const float*)d_in[6];
  const float* ln2s = (const float*)d_in[7];
  const float* ln2b = (const float*)d_in[8];
  const float* w1 = (const float*)d_in[9];
  const float* b1 = (const float*)d_in[10];
  const float* w2 = (const float*)d_in[11];
  const float* b2 = (const float*)d_in[12];

  char* ws = (char*)d_ws;
  unsigned short* wqkv_t = (unsigned short*)(ws);              // [3072,1024]
  unsigned short* wo_t = (unsigned short*)(ws + 6291456);      // [1024,1024]
  unsigned short* w1_t = (unsigned short*)(ws + 8388608);      // [4096,1024]
  unsigned short* w2_t = (unsigned short*)(ws + 16777216);     // [1024,4096]
  unsigned short* h_bf = (unsigned short*)(ws + 25165824);     // [4096,1024] (reused for h2)
  unsigned short* q_bf = (unsigned short*)(ws + 33554432);     // [B,H,S,DH]
  unsigned short* k_bf = (unsigned short*)(ws + 41943040);     // [B,H,S,DH]
  unsigned short* vt_bf = (unsigned short*)(ws + 50331648);    // [B,H,DH,S]
  unsigned short* ctx_bf = (unsigned short*)(ws + 58720256);   // [B,S,D]
  float* mlp_in = (float*)(ws + 67108864);                     // [4096,1024] f32
  unsigned short* g_bf = (unsigned short*)(ws + 83886080);     // [4096,4096]

  dim3 blk(256);
  tcast_kernel<<<dim3(32, 32), blk, 0, stream>>>(wq, wqkv_t, 1024, 1024);
  tcast_kernel<<<dim3(32, 32), blk, 0, stream>>>(wk, wqkv_t + 1048576, 1024, 1024);
  tcast_kernel<<<dim3(32, 32), blk, 0, stream>>>(wv, wqkv_t + 2097152, 1024, 1024);
  tcast_kernel<<<dim3(32, 32), blk, 0, stream>>>(wo, wo_t, 1024, 1024);
  tcast_kernel<<<dim3(128, 32), blk, 0, stream>>>(w1, w1_t, 1024, 4096);
  tcast_kernel<<<dim3(32, 128), blk, 0, stream>>>(w2, w2_t, 4096, 1024);
  ln_kernel<<<dim3(BS_), blk, 0, stream>>>(x, ln1s, ln1b, h_bf);
  gemm_bt<0><<<dim3(24, 32), blk, 0, stream>>>(h_bf, wqkv_t, 1024, nullptr, nullptr,
                                               q_bf, k_bf, vt_bf);
  // q scaled by 1/sqrt(DH) * log2(e) so attention scores are in exp2 domain
  rope_kernel<<<dim3(2048), blk, 0, stream>>>(q_bf, 0.125f * 1.4426950408889634f);
  rope_kernel<<<dim3(2048), blk, 0, stream>>>(k_bf, 1.0f);
  attn_kernel<<<dim3(16, 32), blk, 0, stream>>>(q_bf, k_bf, vt_bf, ctx_bf);
  gemm_bt<1><<<dim3(8, 32), blk, 0, stream>>>(ctx_bf, wo_t, 1024, x, nullptr,
                                              mlp_in, nullptr, nullptr);
  ln_kernel<<<dim3(BS_), blk, 0, stream>>>(mlp_in, ln2s, ln2b, h_bf);
  gemm_bt<2><<<dim3(32, 32), blk, 0, stream>>>(h_bf, w1_t, 1024, b1, nullptr,
                                               g_bf, nullptr, nullptr);
  gemm_bt<3><<<dim3(8, 32), blk, 0, stream>>>(g_bf, w2_t, 4096, b2, mlp_in,
                                              (float*)d_out, nullptr, nullptr);
}